// Round 16
// baseline (561.271 us; speedup 1.0000x reference)
//
#include <hip/hip_runtime.h>

#define NC 96
#define NC3 288
#define NH 256
#define NW 256
#define NHW 65536

typedef unsigned short ushort_t;
typedef __attribute__((ext_vector_type(8))) short bf16x8;
typedef __attribute__((ext_vector_type(4))) float f32x4;
typedef __attribute__((ext_vector_type(4))) unsigned u32x4;

__device__ __forceinline__ ushort_t f2bf(float x) {
  unsigned u = __float_as_uint(x);
  u += 0x7fffu + ((u >> 16) & 1u);
  return (ushort_t)(u >> 16);
}
__device__ __forceinline__ float bf2f(ushort_t h) {
  return __uint_as_float((unsigned)h << 16);
}
// pack fp32 -> u32: low16 = bf16(hi), high16 = bf16(residual)
__device__ __forceinline__ unsigned pack_split(float f) {
  unsigned u = __float_as_uint(f);
  unsigned ur = u + (0x7fffu + ((u >> 16) & 1u));
  const float rem = f - __uint_as_float(ur & 0xffff0000u);
  unsigned v = __float_as_uint(rem);
  v += 0x7fffu + ((v >> 16) & 1u);
  return (ur >> 16) | (v & 0xffff0000u);
}
// unpack u32 -> fp32 (hi + lo)
__device__ __forceinline__ float upk(unsigned u) {
  return __uint_as_float(u << 16) + __uint_as_float(u & 0xffff0000u);
}

union FragU {
  u32x4 u;
  bf16x8 b;
};
// unpack 8 packed u32 (A=c0..3, B=c4..7) -> hi frag + lo frag
__device__ __forceinline__ void unpack8(const uint4 A, const uint4 B,
                                        bf16x8& hf, bf16x8& lf) {
  FragU H, L;
  H.u = (u32x4){__builtin_amdgcn_perm(A.y, A.x, 0x05040100u),
                __builtin_amdgcn_perm(A.w, A.z, 0x05040100u),
                __builtin_amdgcn_perm(B.y, B.x, 0x05040100u),
                __builtin_amdgcn_perm(B.w, B.z, 0x05040100u)};
  L.u = (u32x4){__builtin_amdgcn_perm(A.y, A.x, 0x07060302u),
                __builtin_amdgcn_perm(A.w, A.z, 0x07060302u),
                __builtin_amdgcn_perm(B.y, B.x, 0x07060302u),
                __builtin_amdgcn_perm(B.w, B.z, 0x07060302u)};
  hf = H.b;
  lf = L.b;
}

// ---------------- weight split-bf16 pack prep (once per launch) ------------
__global__ __launch_bounds__(256) void k_wprep(
    const float* __restrict__ qkv_w, const float* __restrict__ proj_w,
    unsigned* __restrict__ wq_pk, unsigned* __restrict__ wp_pk) {
  const int id = blockIdx.x * 256 + threadIdx.x;
  if (id < NC3 * NC)
    wq_pk[id] = pack_split(qkv_w[id]);
  else
    wp_pk[id - NC3 * NC] = pack_split(proj_w[id - NC3 * NC]);
}

// ---------------- 1x1 conv: fused transpose + split-bf16 MFMA GEMM ----------
// v4: weights shared across waves via per-(ocg,kk) packed LDS slice
// wpk[96][36] (13.8KB, padded, 2-way-conflict-free), register-prefetched.
// LDS total 40448B -> 4 blocks/CU. x staged once (xt48 aliases wpk region
// before the step loop). Epilogue LDS-staged coalesced stores (est aliases
// xh/xl).
// TILED: out = packed u32 [(b*1024+sblk)][OUTC][64]; else fp32 [b][o][s].
template <int OUTC, bool TILED>
__global__ __launch_bounds__(256, 4) void k_conv(
    const float* __restrict__ in, const unsigned* __restrict__ w_pk,
    const float* __restrict__ bias, float* __restrict__ out) {
  __shared__ __align__(16) char smem[40448];
  ushort_t* xh = (ushort_t*)smem;             // [64][104] 13312 B
  ushort_t* xl = (ushort_t*)(smem + 13312);   // [64][104] 13312 B
  unsigned* wpk = (unsigned*)(smem + 26624);  // [96][36] u32, 13824 B
  float* xt48 = (float*)(smem + 26624);       // [48][68] 13056 B (pre-loop)
  float* est = (float*)smem;                  // [96][66] epilogue (alias xh/xl)
  const int t = threadIdx.x;
  const int bz = blockIdx.y;
  const int sblk = blockIdx.x;
  const int s0 = sblk * 64;
  const float* xb = in + (size_t)bz * NC * NHW + s0;

  const int lane = t & 63, wave = t >> 6;
  const int ln15 = lane & 15;
  const int akof = (lane >> 4) * 8;  // k-offset in elems (== u32 cols)

  // two-pass transpose+split-pack: 48 channels per pass (xt48 aliases wpk rgn)
#pragma unroll 1
  for (int half = 0; half < 2; ++half) {
    if (half) __syncthreads();  // pack reads of pass 0 complete
#pragma unroll
    for (int i = 0; i < 3; ++i) {
      const int idx = t + 256 * i;  // 768 float4 = 48 rows x 16
      const int row = idx >> 4, c4 = (idx & 15) << 2;
      *(float4*)&xt48[row * 68 + c4] =
          *(const float4*)&xb[(size_t)(half * 48 + row) * NHW + c4];
    }
    __syncthreads();
    {
      const int s = t & 63, cg = t >> 6;
#pragma unroll
      for (int i = 0; i < 6; ++i) {
        const int cl = cg * 12 + i * 2;
        const float f0 = xt48[cl * 68 + s], f1 = xt48[(cl + 1) * 68 + s];
        const ushort_t h0 = f2bf(f0), h1 = f2bf(f1);
        const ushort_t l0 = f2bf(f0 - bf2f(h0)), l1 = f2bf(f1 - bf2f(h1));
        const int c = half * 48 + cl;
        *(unsigned*)&xh[s * 104 + c] = (unsigned)h0 | ((unsigned)h1 << 16);
        *(unsigned*)&xl[s * 104 + c] = (unsigned)l0 | ((unsigned)l1 << 16);
      }
    }
  }
  __syncthreads();
  bf16x8 bH[3], bL[3];
  {
    const int srow = wave * 16 + ln15;
#pragma unroll
    for (int kk = 0; kk < 3; ++kk) {
      bH[kk] = *(const bf16x8*)&xh[srow * 104 + kk * 32 + akof];
      bL[kk] = *(const bf16x8*)&xl[srow * 104 + kk * 32 + akof];
    }
  }

  constexpr int S = 3 * (OUTC / 96);
  const int sl = wave * 16 + ln15;
  // staging decomposition: 768 uint4 per slice; thread loads j = t + 256*i
  const int srow0 = t >> 3, scq = t & 7;  // row/col-quad for i=0 (rows 0..31)
  // preload step 0 slice (ocg=0, kk=0)
  uint4 wreg[3];
#pragma unroll
  for (int i = 0; i < 3; ++i) {
    const int row = srow0 + i * 32;
    wreg[i] = *(const uint4*)(w_pk + (size_t)row * NC + scq * 4);
  }

  f32x4 acc[6];
#pragma unroll
  for (int step = 0; step < S; ++step) {
    const int ocg = step / 3, kk = step % 3;
    __syncthreads();  // prior wpk reads (or xt48 pack reads at step 0) done
#pragma unroll
    for (int i = 0; i < 3; ++i)
      *(uint4*)&wpk[(srow0 + i * 32) * 36 + scq * 4] = wreg[i];
    __syncthreads();
    // prefetch next slice into regs (overlaps MFMA + unpack)
    if (step + 1 < S) {
      const int nocg = (step + 1) / 3, nkk = (step + 1) % 3;
#pragma unroll
      for (int i = 0; i < 3; ++i) {
        const int row = srow0 + i * 32;
        wreg[i] = *(const uint4*)(w_pk + (size_t)(nocg * 96 + row) * NC +
                                  nkk * 32 + scq * 4);
      }
    }
    if (kk == 0) {
#pragma unroll
      for (int m = 0; m < 6; ++m) acc[m] = (f32x4){0.f, 0.f, 0.f, 0.f};
    }
#pragma unroll
    for (int m = 0; m < 6; ++m) {
      const int base = (m * 16 + ln15) * 36 + akof;
      const uint4 A = *(const uint4*)&wpk[base];
      const uint4 B = *(const uint4*)&wpk[base + 4];
      bf16x8 aH, aL;
      unpack8(A, B, aH, aL);
      acc[m] = __builtin_amdgcn_mfma_f32_16x16x32_bf16(aH, bH[kk], acc[m], 0, 0, 0);
      acc[m] = __builtin_amdgcn_mfma_f32_16x16x32_bf16(aH, bL[kk], acc[m], 0, 0, 0);
      acc[m] = __builtin_amdgcn_mfma_f32_16x16x32_bf16(aL, bH[kk], acc[m], 0, 0, 0);
    }
    // epilogue after the last kk of this oc-group: LDS-staged coalesced store
    if (kk == 2) {
      __syncthreads();  // wpk reads done; est region free
#pragma unroll
      for (int m = 0; m < 6; ++m) {
        const int o2 = m * 16 + (lane >> 4) * 4;
#pragma unroll
        for (int r = 0; r < 4; ++r) est[(o2 + r) * 66 + sl] = acc[m][r];
      }
      __syncthreads();
      if (TILED) {
        unsigned* ob = (unsigned*)out +
                       ((size_t)(bz * 1024 + sblk)) * OUTC * 64 +
                       (size_t)ocg * 96 * 64;
#pragma unroll
        for (int j = 0; j < 6; ++j) {
          const int idx = t + 256 * j;
          const int row = idx >> 4, c4 = (idx & 15) << 2;
          const float bs = bias[ocg * 96 + row];
          uint4 pkv;
          pkv.x = pack_split(est[row * 66 + c4 + 0] + bs);
          pkv.y = pack_split(est[row * 66 + c4 + 1] + bs);
          pkv.z = pack_split(est[row * 66 + c4 + 2] + bs);
          pkv.w = pack_split(est[row * 66 + c4 + 3] + bs);
          *(uint4*)(ob + (size_t)row * 64 + c4) = pkv;
        }
      } else {
        float* ob = out + (size_t)bz * OUTC * NHW + s0;
#pragma unroll
        for (int j = 0; j < 6; ++j) {
          const int idx = t + 256 * j;
          const int row = idx >> 4, c4 = (idx & 15) << 2;
          const float bs = bias[ocg * 96 + row];
          const float4 v = make_float4(
              est[row * 66 + c4] + bs, est[row * 66 + c4 + 1] + bs,
              est[row * 66 + c4 + 2] + bs, est[row * 66 + c4 + 3] + bs);
          *(float4*)(ob + (size_t)(ocg * 96 + row) * NHW + c4) = v;
        }
      }
    }
  }
}

// ---------------- depthwise 3x3 + layout emit + norm partials ----------------
// q/k -> qt/kt in 16-h granules [bc][hb16][w][16h] (fully coalesced stores)
// v   -> v_pk  [bc][wb][h][32w] u32 (hi|lo<<16)
__global__ __launch_bounds__(256, 8) void k_dw3(
    const unsigned* __restrict__ qkvt, const float* __restrict__ w,
    const float* __restrict__ bias, ushort_t* __restrict__ qt_hi,
    ushort_t* __restrict__ qt_lo, ushort_t* __restrict__ kt_hi,
    ushort_t* __restrict__ kt_lo, unsigned* __restrict__ v_pk,
    float* __restrict__ nq_p, float* __restrict__ nk_p) {
  __shared__ float sd[18][264];
  const int t = threadIdx.x;
  const int hb = blockIdx.x;
  const int bcc = blockIdx.y;
  const int b = bcc / NC3, ch = bcc % NC3;
  const int h0 = hb * 16;
  const unsigned* src = qkvt + (size_t)b * 1024 * NC3 * 64 + (size_t)ch * 64;
#pragma unroll
  for (int i = 0; i < 5; ++i) {
    const int idx = t + 256 * i;
    if (idx < 18 * 64) {
      const int r = idx >> 6, j = idx & 63;
      const int gh = h0 + r - 1;
      float4 v = make_float4(0.f, 0.f, 0.f, 0.f);
      if (gh >= 0 && gh < 256) {
        const int gw = 4 * j;
        const uint4 pv = *(const uint4*)&src[(size_t)(gh * 4 + (gw >> 6)) *
                                                 (NC3 * 64) +
                                             (gw & 63)];
        v = make_float4(upk(pv.x), upk(pv.y), upk(pv.z), upk(pv.w));
      }
      *(float4*)&sd[r][4 + 4 * j] = v;
    }
  }
  if (t < 36) {
    const int r = t >> 1;
    sd[r][(t & 1) ? 260 : 3] = 0.f;
  }
  __syncthreads();
  float wr[9];
#pragma unroll
  for (int k = 0; k < 9; ++k) wr[k] = w[ch * 9 + k];
  const float bs = bias[ch];
  const int wl = t;
  float res[16];
  float r0a = sd[0][wl + 3], r0b = sd[0][wl + 4], r0c = sd[0][wl + 5];
  float r1a = sd[1][wl + 3], r1b = sd[1][wl + 4], r1c = sd[1][wl + 5];
#pragma unroll
  for (int r = 0; r < 16; ++r) {
    const float r2a = sd[r + 2][wl + 3], r2b = sd[r + 2][wl + 4],
                r2c = sd[r + 2][wl + 5];
    float a = bs;
    a = fmaf(r0a, wr[0], a);
    a = fmaf(r0b, wr[1], a);
    a = fmaf(r0c, wr[2], a);
    a = fmaf(r1a, wr[3], a);
    a = fmaf(r1b, wr[4], a);
    a = fmaf(r1c, wr[5], a);
    a = fmaf(r2a, wr[6], a);
    a = fmaf(r2b, wr[7], a);
    a = fmaf(r2c, wr[8], a);
    res[r] = a;
    r0a = r1a; r0b = r1b; r0c = r1c;
    r1a = r2a; r1b = r2b; r1c = r2c;
  }
  if (ch < 192) {
    const int qk = ch / 96, c = ch - qk * 96;
    const int bc = b * 96 + c;
    float ss = 0.f;
#pragma unroll
    for (int r = 0; r < 16; ++r) ss = fmaf(res[r], res[r], ss);
    (qk ? nk_p : nq_p)[(size_t)bc * 4096 + hb * 256 + wl] = ss;
    // 16-h granule layout: [bc][hb16][w][16]
    const size_t tb = (size_t)bc * NHW + (size_t)hb * 4096 + (size_t)wl * 16;
    ushort_t* dh = (qk ? kt_hi : qt_hi) + tb;
    ushort_t* dl = (qk ? kt_lo : qt_lo) + tb;
#pragma unroll
    for (int j4 = 0; j4 < 2; ++j4) {
      uint4 H, L;
      unsigned* ph = (unsigned*)&H;
      unsigned* pl = (unsigned*)&L;
#pragma unroll
      for (int e = 0; e < 4; ++e) {
        const float f0 = res[j4 * 8 + 2 * e], f1 = res[j4 * 8 + 2 * e + 1];
        const ushort_t hh0 = f2bf(f0), hh1 = f2bf(f1);
        ph[e] = (unsigned)hh0 | ((unsigned)hh1 << 16);
        pl[e] = (unsigned)f2bf(f0 - bf2f(hh0)) |
                ((unsigned)f2bf(f1 - bf2f(hh1)) << 16);
      }
      *(uint4*)(dh + j4 * 8) = H;
      *(uint4*)(dl + j4 * 8) = L;
    }
  } else {
    const int bc = b * 96 + (ch - 192);
    const int wb = wl >> 5, wsub = wl & 31;
    unsigned* dp = v_pk + (size_t)bc * NHW + wb * 8192 + wsub;
#pragma unroll
    for (int r = 0; r < 16; ++r) {
      const float f = res[r];
      const ushort_t hh = f2bf(f);
      dp[(h0 + r) * 32] = (unsigned)hh | ((unsigned)f2bf(f - bf2f(hh)) << 16);
    }
  }
}

// ---------------- attn: S = QT*K (split-bf16 MFMA) * iq*ik*temp,
// col-softmax over w, P -> pt tiled [bc][wb][v][32w] split bf16 ----
__global__ __launch_bounds__(256, 3) void k_attn_mfma(
    const ushort_t* __restrict__ qt_hi, const ushort_t* __restrict__ qt_lo,
    const ushort_t* __restrict__ kt_hi, const ushort_t* __restrict__ kt_lo,
    const float* __restrict__ nq_p, const float* __restrict__ nk_p,
    const float* __restrict__ temp, ushort_t* __restrict__ pt_hi,
    ushort_t* __restrict__ pt_lo) {
  __shared__ __align__(16) char smem[52480];
  ushort_t* qh = (ushort_t*)smem;
  ushort_t* ql = (ushort_t*)(smem + 20480);
  ushort_t* kh = (ushort_t*)(smem + 40960);
  ushort_t* kl = (ushort_t*)(smem + 46080);
  float* red = (float*)(smem + 51200);
  float* iqs = red;
  float* iks = (float*)(smem + 52224);
  ushort_t* pts = (ushort_t*)smem;

  const int t = threadIdx.x;
  const int lane = t & 63;
  const int wid = t >> 6;
  const int bid = blockIdx.x;
  const int pxb = gridDim.x >> 5;
  const int bc = (bid & 7) * pxb + (bid >> 5);
  const int v0 = ((bid >> 3) & 3) * 64;
  const size_t base_q = (size_t)bc * NHW;
  const size_t base_k = (size_t)bc * NHW;

  f32x4 acc[4][4];
#pragma unroll
  for (int mt = 0; mt < 4; ++mt)
#pragma unroll
    for (int nt = 0; nt < 4; ++nt) acc[mt][nt] = (f32x4){0.f, 0.f, 0.f, 0.f};

  for (int hb = 0; hb < 8; ++hb) {
    {
      // Q: two 16-h granules -> qh row [t][32h]
      const ushort_t* g0 = qt_hi + base_q + (size_t)(2 * hb) * 4096 + t * 16;
      const ushort_t* g1 = g0 + 4096;
      const ushort_t* gl0 = qt_lo + base_q + (size_t)(2 * hb) * 4096 + t * 16;
      const ushort_t* gl1 = gl0 + 4096;
      uint4* dh = (uint4*)(qh + t * 40);
      uint4* dl = (uint4*)(ql + t * 40);
      dh[0] = *(const uint4*)(g0);
      dh[1] = *(const uint4*)(g0 + 8);
      dh[2] = *(const uint4*)(g1);
      dh[3] = *(const uint4*)(g1 + 8);
      dl[0] = *(const uint4*)(gl0);
      dl[1] = *(const uint4*)(gl0 + 8);
      dl[2] = *(const uint4*)(gl1);
      dl[3] = *(const uint4*)(gl1 + 8);
      if (t < 64) {
        const ushort_t* k0 =
            kt_hi + base_k + (size_t)(2 * hb) * 4096 + (size_t)(v0 + t) * 16;
        const ushort_t* k1 = k0 + 4096;
        uint4* dk = (uint4*)(kh + t * 40);
        dk[0] = *(const uint4*)(k0);
        dk[1] = *(const uint4*)(k0 + 8);
        dk[2] = *(const uint4*)(k1);
        dk[3] = *(const uint4*)(k1 + 8);
      } else if (t < 128) {
        const int r = t - 64;
        const ushort_t* k0 =
            kt_lo + base_k + (size_t)(2 * hb) * 4096 + (size_t)(v0 + r) * 16;
        const ushort_t* k1 = k0 + 4096;
        uint4* dk = (uint4*)(kl + r * 40);
        dk[0] = *(const uint4*)(k0);
        dk[1] = *(const uint4*)(k0 + 8);
        dk[2] = *(const uint4*)(k1);
        dk[3] = *(const uint4*)(k1 + 8);
      }
    }
    __syncthreads();
    bf16x8 aH[4], aL[4];
#pragma unroll
    for (int mt = 0; mt < 4; ++mt) {
      const int off = (wid * 64 + mt * 16 + (lane & 15)) * 40 + (lane >> 4) * 8;
      aH[mt] = *(const bf16x8*)(qh + off);
      aL[mt] = *(const bf16x8*)(ql + off);
    }
#pragma unroll
    for (int nt = 0; nt < 4; ++nt) {
      const int off = (nt * 16 + (lane & 15)) * 40 + (lane >> 4) * 8;
      const bf16x8 bH = *(const bf16x8*)(kh + off);
      const bf16x8 bL = *(const bf16x8*)(kl + off);
#pragma unroll
      for (int mt = 0; mt < 4; ++mt) {
        acc[mt][nt] = __builtin_amdgcn_mfma_f32_16x16x32_bf16(aH[mt], bH, acc[mt][nt], 0, 0, 0);
        acc[mt][nt] = __builtin_amdgcn_mfma_f32_16x16x32_bf16(aH[mt], bL, acc[mt][nt], 0, 0, 0);
        acc[mt][nt] = __builtin_amdgcn_mfma_f32_16x16x32_bf16(aL[mt], bH, acc[mt][nt], 0, 0, 0);
      }
    }
    __syncthreads();
  }

  {
    float s8 = 0.f;
    const float* np = nq_p + (size_t)bc * 4096 + t;
#pragma unroll
    for (int hb = 0; hb < 16; ++hb) s8 += np[hb * 256];
    iqs[t] = 1.f / fmaxf(sqrtf(s8), 1e-12f);
    if (t < 64) {
      float sk8 = 0.f;
      const float* nk = nk_p + (size_t)bc * 4096 + v0 + t;
#pragma unroll
      for (int hb = 0; hb < 16; ++hb) sk8 += nk[hb * 256];
      iks[t] = temp[bc % NC] / fmaxf(sqrtf(sk8), 1e-12f);
    }
  }
  __syncthreads();
#pragma unroll
  for (int mt = 0; mt < 4; ++mt) {
    float iq4[4];
#pragma unroll
    for (int r = 0; r < 4; ++r)
      iq4[r] = iqs[wid * 64 + mt * 16 + (lane >> 4) * 4 + r];
#pragma unroll
    for (int nt = 0; nt < 4; ++nt) {
      const float ikv = iks[nt * 16 + (lane & 15)];
#pragma unroll
      for (int r = 0; r < 4; ++r) acc[mt][nt][r] *= iq4[r] * ikv;
    }
  }
  __syncthreads();

  float Mv[4], Sv[4];
#pragma unroll
  for (int nt = 0; nt < 4; ++nt) {
    float m = -3.4e38f;
#pragma unroll
    for (int mt = 0; mt < 4; ++mt)
#pragma unroll
      for (int r = 0; r < 4; ++r) m = fmaxf(m, acc[mt][nt][r]);
    m = fmaxf(m, __shfl_xor(m, 16));
    m = fmaxf(m, __shfl_xor(m, 32));
    if (lane < 16) red[wid * 64 + nt * 16 + lane] = m;
  }
  __syncthreads();
#pragma unroll
  for (int nt = 0; nt < 4; ++nt) {
    const int vl = nt * 16 + (lane & 15);
    Mv[nt] = fmaxf(fmaxf(red[vl], red[64 + vl]),
                   fmaxf(red[128 + vl], red[192 + vl]));
  }
  __syncthreads();
#pragma unroll
  for (int nt = 0; nt < 4; ++nt) {
    float s = 0.f;
#pragma unroll
    for (int mt = 0; mt < 4; ++mt)
#pragma unroll
      for (int r = 0; r < 4; ++r) {
        const float p = __expf(acc[mt][nt][r] - Mv[nt]);
        acc[mt][nt][r] = p;
        s += p;
      }
    s += __shfl_xor(s, 16);
    s += __shfl_xor(s, 32);
    if (lane < 16) red[wid * 64 + nt * 16 + lane] = s;
  }
  __syncthreads();
#pragma unroll
  for (int nt = 0; nt < 4; ++nt) {
    const int vl = nt * 16 + (lane & 15);
    Sv[nt] = 1.f / (red[vl] + red[64 + vl] + red[128 + vl] + red[192 + vl]);
  }
#pragma unroll
  for (int nt = 0; nt < 4; ++nt)
#pragma unroll
    for (int mt = 0; mt < 4; ++mt)
#pragma unroll
      for (int r = 0; r < 4; ++r) acc[mt][nt][r] *= Sv[nt];
  __syncthreads();

  for (int pass = 0; pass < 2; ++pass) {
#pragma unroll
    for (int nt = 0; nt < 4; ++nt)
#pragma unroll
      for (int mt = 0; mt < 4; ++mt) {
        ushort_t pk[4];
#pragma unroll
        for (int r = 0; r < 4; ++r) {
          const float p = acc[mt][nt][r];
          const ushort_t hi = f2bf(p);
          pk[r] = pass == 0 ? hi : f2bf(p - bf2f(hi));
        }
        const int v = nt * 16 + (lane & 15);
        const int wb2 = wid * 64 + mt * 16 + ((lane >> 4) << 2);
        *(ushort4*)(pts + v * 264 + wb2) =
            make_ushort4(pk[0], pk[1], pk[2], pk[3]);
      }
    __syncthreads();
    ushort_t* dst = pass == 0 ? pt_hi : pt_lo;
#pragma unroll
    for (int i = 0; i < 2; ++i) {
      const int cid = t + (i << 8);
      const int wb = cid >> 6, v = cid & 63;
      const ushort_t* sp = pts + v * 264 + wb * 32;
      ushort_t* d = dst + (size_t)bc * NHW + (size_t)wb * 8192 +
                    (size_t)(v0 + v) * 32;
#pragma unroll
      for (int j = 0; j < 4; ++j)
        *(uint4*)(d + j * 8) = *(const uint4*)(sp + j * 8);
    }
    __syncthreads();
  }
}

// ---------------- out[h][v] = sum_w V[h][w] * P[w][v], split-bf16 MFMA ----
__global__ __launch_bounds__(256, 3) void k_av_mfma(
    const unsigned* __restrict__ v_pk, const ushort_t* __restrict__ pt_hi,
    const ushort_t* __restrict__ pt_lo, float* __restrict__ aout) {
  __shared__ __align__(16) ushort_t vh[128 * 40];
  __shared__ __align__(16) ushort_t vl[128 * 40];
  __shared__ __align__(16) ushort_t ph[128 * 40];
  __shared__ __align__(16) ushort_t pl[128 * 40];
  const int t = threadIdx.x;
  const int lane = t & 63;
  const int wid = t >> 6;
  const int bid = blockIdx.x;
  const int pxb = gridDim.x >> 5;
  const int bc = (bid & 7) * pxb + (bid >> 5);
  const int tile = (bid >> 3) & 3;
  const int h0 = (tile >> 1) * 128, v0 = (tile & 1) * 128;
  const int wh = wid >> 1, wv = wid & 1;

  f32x4 acc[4][4];
#pragma unroll
  for (int mt = 0; mt < 4; ++mt)
#pragma unroll
    for (int nt = 0; nt < 4; ++nt) acc[mt][nt] = (f32x4){0.f, 0.f, 0.f, 0.f};

  for (int wb = 0; wb < 8; ++wb) {
#pragma unroll
    for (int i = 0; i < 4; ++i) {
      const int id = t + (i << 8);
      const int row = id >> 3, q = id & 7;
      const uint4 pk = *(const uint4*)(v_pk + (size_t)bc * NHW + wb * 8192 +
                                       (size_t)(h0 + row) * 32 + q * 4);
      const ushort4 hi4 =
          make_ushort4((ushort_t)(pk.x & 0xffff), (ushort_t)(pk.y & 0xffff),
                       (ushort_t)(pk.z & 0xffff), (ushort_t)(pk.w & 0xffff));
      const ushort4 lo4 =
          make_ushort4((ushort_t)(pk.x >> 16), (ushort_t)(pk.y >> 16),
                       (ushort_t)(pk.z >> 16), (ushort_t)(pk.w >> 16));
      *(ushort4*)(vh + row * 40 + q * 4) = hi4;
      *(ushort4*)(vl + row * 40 + q * 4) = lo4;
    }
#pragma unroll
    for (int i = 0; i < 4; ++i) {
      const int id = t + (i << 8);
      const int arr = id >> 9, rem = id & 511;
      const int row = rem >> 2, q = rem & 3;
      const ushort_t* g = (arr ? pt_lo : pt_hi) + (size_t)bc * NHW +
                          wb * 8192 + (size_t)(v0 + row) * 32 + q * 8;
      ushort_t* d = (arr ? pl : ph) + row * 40 + q * 8;
      *(uint4*)d = *(const uint4*)g;
    }
    __syncthreads();
    bf16x8 aH[4], aL[4];
#pragma unroll
    for (int mt = 0; mt < 4; ++mt) {
      const int off = (wh * 64 + mt * 16 + (lane & 15)) * 40 + (lane >> 4) * 8;
      aH[mt] = *(const bf16x8*)(vh + off);
      aL[mt] = *(const bf16x8*)(vl + off);
    }
#pragma unroll
    for (int nt = 0; nt < 4; ++nt) {
      const int off = (wv * 64 + nt * 16 + (lane & 15)) * 40 + (lane >> 4) * 8;
      const bf16x8 bH = *(const bf16x8*)(ph + off);
      const bf16x8 bL = *(const bf16x8*)(pl + off);
#pragma unroll
      for (int mt = 0; mt < 4; ++mt) {
        acc[mt][nt] = __builtin_amdgcn_mfma_f32_16x16x32_bf16(aH[mt], bH, acc[mt][nt], 0, 0, 0);
        acc[mt][nt] = __builtin_amdgcn_mfma_f32_16x16x32_bf16(aH[mt], bL, acc[mt][nt], 0, 0, 0);
        acc[mt][nt] = __builtin_amdgcn_mfma_f32_16x16x32_bf16(aL[mt], bH, acc[mt][nt], 0, 0, 0);
      }
    }
    __syncthreads();
  }

#pragma unroll
  for (int mt = 0; mt < 4; ++mt) {
    const int hbase = h0 + wh * 64 + mt * 16 + ((lane >> 4) << 2);
#pragma unroll
    for (int nt = 0; nt < 4; ++nt) {
      const int vv = v0 + wv * 64 + nt * 16 + (lane & 15);
      float* o = aout + (size_t)bc * NHW + (size_t)hbase * NW + vv;
#pragma unroll
      for (int r = 0; r < 4; ++r) o[(size_t)r * NW] = acc[mt][nt][r];
    }
  }
}

extern "C" void kernel_launch(void* const* d_in, const int* in_sizes, int n_in,
                              void* d_out, int out_size, void* d_ws,
                              size_t ws_size, hipStream_t stream) {
  const float* x = (const float*)d_in[0];
  const float* qkv_w = (const float*)d_in[1];
  const float* qkv_b = (const float*)d_in[2];
  const float* dw_w = (const float*)d_in[3];
  const float* dw_b = (const float*)d_in[4];
  const float* temp = (const float*)d_in[5];
  const float* proj_w = (const float*)d_in[6];
  const float* proj_b = (const float*)d_in[7];
  float* out = (float*)d_out;

  auto need = [](int nb) -> size_t {
    return (size_t)nb * 154140672ull + 147456ull;
  };
  int nb = 1;
  if (need(4) <= ws_size) nb = 4;
  else if (need(2) <= ws_size) nb = 2;

  char* base = (char*)d_ws;
  const size_t QKV_T = (size_t)nb * 75497472ull;  // region reserved; packed uses 1/2
  const size_t HALF = (size_t)nb * 12582912ull;
  const size_t NQB = (size_t)nb * 1572864ull;
  unsigned* qkv_tiled = (unsigned*)base;  // packed u32, nb*37748736 bytes
  ushort_t* pt_hi = (ushort_t*)base;      // alias (qkv dead after dw3)
  ushort_t* pt_lo = (ushort_t*)(base + HALF);
  float* aout = (float*)(base + 2 * HALF);
  char* p = base + QKV_T;
  ushort_t* qt_hi = (ushort_t*)p; p += HALF;
  ushort_t* qt_lo = (ushort_t*)p; p += HALF;
  ushort_t* kt_hi = (ushort_t*)p; p += HALF;
  ushort_t* kt_lo = (ushort_t*)p; p += HALF;
  unsigned* v_pk = (unsigned*)p; p += 2 * HALF;
  float* nq_p = (float*)p; p += NQB;
  float* nk_p = (float*)p; p += NQB;
  unsigned* wq_pk = (unsigned*)p; p += (size_t)NC3 * NC * 4;  // 110592 B
  unsigned* wp_pk = (unsigned*)p;                             // 36864 B

  k_wprep<<<dim3(144), 256, 0, stream>>>(qkv_w, proj_w, wq_pk, wp_pk);

  const int BC = nb * NC;
  for (int b0 = 0; b0 < 4; b0 += nb) {
    const float* xb = x + (size_t)b0 * NC * NHW;
    float* outb = out + (size_t)b0 * NC * NHW;
    k_conv<NC3, true><<<dim3(1024, nb), 256, 0, stream>>>(
        xb, wq_pk, qkv_b, (float*)qkv_tiled);
    k_dw3<<<dim3(16, nb * NC3), 256, 0, stream>>>(
        qkv_tiled, dw_w, dw_b, qt_hi, qt_lo, kt_hi, kt_lo, v_pk, nq_p, nk_p);
    k_attn_mfma<<<dim3(BC * 4), 256, 0, stream>>>(
        qt_hi, qt_lo, kt_hi, kt_lo, nq_p, nk_p, temp, pt_hi, pt_lo);
    k_av_mfma<<<dim3(BC * 4), 256, 0, stream>>>(v_pk, pt_hi, pt_lo, aout);
    k_conv<NC, false><<<dim3(1024, nb), 256, 0, stream>>>(
        aout, wp_pk, proj_b, outb);
  }
}

// Round 18
// 520.299 us; speedup vs baseline: 1.0787x; 1.0787x over previous
//
#include <hip/hip_runtime.h>

#define NC 96
#define NC3 288
#define NH 256
#define NW 256
#define NHW 65536

typedef unsigned short ushort_t;
typedef __attribute__((ext_vector_type(8))) short bf16x8;
typedef __attribute__((ext_vector_type(4))) float f32x4;

__device__ __forceinline__ ushort_t f2bf(float x) {
  unsigned u = __float_as_uint(x);
  u += 0x7fffu + ((u >> 16) & 1u);
  return (ushort_t)(u >> 16);
}
__device__ __forceinline__ float bf2f(ushort_t h) {
  return __uint_as_float((unsigned)h << 16);
}
// pack fp32 -> u32: low16 = bf16(hi), high16 = bf16(residual)
__device__ __forceinline__ unsigned pack_split(float f) {
  unsigned u = __float_as_uint(f);
  unsigned ur = u + (0x7fffu + ((u >> 16) & 1u));
  const float rem = f - __uint_as_float(ur & 0xffff0000u);
  unsigned v = __float_as_uint(rem);
  v += 0x7fffu + ((v >> 16) & 1u);
  return (ur >> 16) | (v & 0xffff0000u);
}
// unpack u32 -> fp32 (hi + lo)
__device__ __forceinline__ float upk(unsigned u) {
  return __uint_as_float(u << 16) + __uint_as_float(u & 0xffff0000u);
}

// ---------------- weight split-bf16 prep (once per launch) ----------------
__global__ __launch_bounds__(256) void k_wprep(
    const float* __restrict__ qkv_w, const float* __restrict__ proj_w,
    ushort_t* __restrict__ wq_hi, ushort_t* __restrict__ wq_lo,
    ushort_t* __restrict__ wp_hi, ushort_t* __restrict__ wp_lo) {
  const int id = blockIdx.x * 256 + threadIdx.x;
  if (id < NC3 * NC) {
    const float v = qkv_w[id];
    const ushort_t h = f2bf(v);
    wq_hi[id] = h;
    wq_lo[id] = f2bf(v - bf2f(h));
  } else {
    const int j = id - NC3 * NC;  // < NC*NC
    const float v = proj_w[j];
    const ushort_t h = f2bf(v);
    wp_hi[j] = h;
    wp_lo[j] = f2bf(v - bf2f(h));
  }
}

// ---------------- 1x1 conv: fused transpose + split-bf16 MFMA GEMM ----------
// v3 (best-measured): two-pass transpose (xt48) + direct global weight loads
// + epilogue staged over dead xh/xl. 39.9KB LDS, 4 blocks/CU.
// TILED: out = packed u32 [(b*1024+sblk)][OUTC][64]; else fp32 [b][o][s].
template <int OUTC, bool TILED>
__global__ __launch_bounds__(256, 4) void k_conv(
    const float* __restrict__ in, const ushort_t* __restrict__ w_hi,
    const ushort_t* __restrict__ w_lo, const float* __restrict__ bias,
    float* __restrict__ out) {
  __shared__ __align__(16) char smem[39936];
  ushort_t* xh = (ushort_t*)smem;            // [64][104]
  ushort_t* xl = (ushort_t*)(smem + 13312);  // [64][104]
  float* xt48 = (float*)(smem + 26624);      // [48][68]
  float* est = (float*)smem;                 // [96][66] epilogue stage (alias)
  const int t = threadIdx.x;
  const int bz = blockIdx.y;
  const int sblk = blockIdx.x;
  const int s0 = sblk * 64;
  const float* xb = in + (size_t)bz * NC * NHW + s0;

  const int lane = t & 63, wave = t >> 6;
  const int ln15 = lane & 15;
  const int akof = (lane >> 4) * 8;

  // two-pass transpose+split-pack: 48 channels per pass
#pragma unroll 1
  for (int half = 0; half < 2; ++half) {
    if (half) __syncthreads();  // pack reads of pass 0 complete
#pragma unroll
    for (int i = 0; i < 3; ++i) {
      const int idx = t + 256 * i;  // 768 float4 = 48 rows x 16
      const int row = idx >> 4, c4 = (idx & 15) << 2;
      *(float4*)&xt48[row * 68 + c4] =
          *(const float4*)&xb[(size_t)(half * 48 + row) * NHW + c4];
    }
    __syncthreads();
    {
      const int s = t & 63, cg = t >> 6;
#pragma unroll
      for (int i = 0; i < 6; ++i) {
        const int cl = cg * 12 + i * 2;
        const float f0 = xt48[cl * 68 + s], f1 = xt48[(cl + 1) * 68 + s];
        const ushort_t h0 = f2bf(f0), h1 = f2bf(f1);
        const ushort_t l0 = f2bf(f0 - bf2f(h0)), l1 = f2bf(f1 - bf2f(h1));
        const int c = half * 48 + cl;
        *(unsigned*)&xh[s * 104 + c] = (unsigned)h0 | ((unsigned)h1 << 16);
        *(unsigned*)&xl[s * 104 + c] = (unsigned)l0 | ((unsigned)l1 << 16);
      }
    }
  }
  __syncthreads();
  bf16x8 bH[3], bL[3];
  {
    const int srow = wave * 16 + ln15;
#pragma unroll
    for (int kk = 0; kk < 3; ++kk) {
      bH[kk] = *(const bf16x8*)&xh[srow * 104 + kk * 32 + akof];
      bL[kk] = *(const bf16x8*)&xl[srow * 104 + kk * 32 + akof];
    }
  }

  constexpr int S = 3 * (OUTC / 96);
  const int sl = wave * 16 + ln15;
  f32x4 acc[6];
#pragma unroll
  for (int step = 0; step < S; ++step) {
    const int ocg = step / 3, kk = step % 3;
    if (kk == 0) {
#pragma unroll
      for (int m = 0; m < 6; ++m) acc[m] = (f32x4){0.f, 0.f, 0.f, 0.f};
    }
#pragma unroll
    for (int m = 0; m < 6; ++m) {
      const int wi = (ocg * 96 + m * 16 + ln15) * NC + kk * 32 + akof;
      const bf16x8 aH = *(const bf16x8*)(w_hi + wi);
      const bf16x8 aL = *(const bf16x8*)(w_lo + wi);
      acc[m] = __builtin_amdgcn_mfma_f32_16x16x32_bf16(aH, bH[kk], acc[m], 0, 0, 0);
      acc[m] = __builtin_amdgcn_mfma_f32_16x16x32_bf16(aH, bL[kk], acc[m], 0, 0, 0);
      acc[m] = __builtin_amdgcn_mfma_f32_16x16x32_bf16(aL, bH[kk], acc[m], 0, 0, 0);
    }
    // epilogue after the last kk of this oc-group: LDS-staged coalesced store
    if (kk == 2) {
      __syncthreads();  // xh/xl frag reads done (ocg0) / prior est reads done
#pragma unroll
      for (int m = 0; m < 6; ++m) {
        const int o2 = m * 16 + (lane >> 4) * 4;
#pragma unroll
        for (int r = 0; r < 4; ++r) est[(o2 + r) * 66 + sl] = acc[m][r];
      }
      __syncthreads();
      if (TILED) {
        unsigned* ob = (unsigned*)out +
                       ((size_t)(bz * 1024 + sblk)) * OUTC * 64 +
                       (size_t)ocg * 96 * 64;
#pragma unroll
        for (int j = 0; j < 6; ++j) {
          const int idx = t + 256 * j;
          const int row = idx >> 4, c4 = (idx & 15) << 2;
          const float bs = bias[ocg * 96 + row];
          uint4 pkv;
          pkv.x = pack_split(est[row * 66 + c4 + 0] + bs);
          pkv.y = pack_split(est[row * 66 + c4 + 1] + bs);
          pkv.z = pack_split(est[row * 66 + c4 + 2] + bs);
          pkv.w = pack_split(est[row * 66 + c4 + 3] + bs);
          *(uint4*)(ob + (size_t)row * 64 + c4) = pkv;
        }
      } else {
        float* ob = out + (size_t)bz * OUTC * NHW + s0;
#pragma unroll
        for (int j = 0; j < 6; ++j) {
          const int idx = t + 256 * j;
          const int row = idx >> 4, c4 = (idx & 15) << 2;
          const float bs = bias[ocg * 96 + row];
          const float4 v = make_float4(
              est[row * 66 + c4] + bs, est[row * 66 + c4 + 1] + bs,
              est[row * 66 + c4 + 2] + bs, est[row * 66 + c4 + 3] + bs);
          *(float4*)(ob + (size_t)(ocg * 96 + row) * NHW + c4) = v;
        }
      }
    }
  }
}

// ---------------- depthwise 3x3 + layout emit + norm partials ----------------
// q/k -> qt/kt in 16-h granules [bc][hb16][w][16h] (fully coalesced stores)
// v   -> v_pk  [bc][wb][h][32w] u32 (hi|lo<<16)
__global__ __launch_bounds__(256, 8) void k_dw3(
    const unsigned* __restrict__ qkvt, const float* __restrict__ w,
    const float* __restrict__ bias, ushort_t* __restrict__ qt_hi,
    ushort_t* __restrict__ qt_lo, ushort_t* __restrict__ kt_hi,
    ushort_t* __restrict__ kt_lo, unsigned* __restrict__ v_pk,
    float* __restrict__ nq_p, float* __restrict__ nk_p) {
  __shared__ float sd[18][264];
  const int t = threadIdx.x;
  const int hb = blockIdx.x;
  const int bcc = blockIdx.y;
  const int b = bcc / NC3, ch = bcc % NC3;
  const int h0 = hb * 16;
  const unsigned* src = qkvt + (size_t)b * 1024 * NC3 * 64 + (size_t)ch * 64;
#pragma unroll
  for (int i = 0; i < 5; ++i) {
    const int idx = t + 256 * i;
    if (idx < 18 * 64) {
      const int r = idx >> 6, j = idx & 63;
      const int gh = h0 + r - 1;
      float4 v = make_float4(0.f, 0.f, 0.f, 0.f);
      if (gh >= 0 && gh < 256) {
        const int gw = 4 * j;
        const uint4 pv = *(const uint4*)&src[(size_t)(gh * 4 + (gw >> 6)) *
                                                 (NC3 * 64) +
                                             (gw & 63)];
        v = make_float4(upk(pv.x), upk(pv.y), upk(pv.z), upk(pv.w));
      }
      *(float4*)&sd[r][4 + 4 * j] = v;
    }
  }
  if (t < 36) {
    const int r = t >> 1;
    sd[r][(t & 1) ? 260 : 3] = 0.f;
  }
  __syncthreads();
  float wr[9];
#pragma unroll
  for (int k = 0; k < 9; ++k) wr[k] = w[ch * 9 + k];
  const float bs = bias[ch];
  const int wl = t;
  float res[16];
  float r0a = sd[0][wl + 3], r0b = sd[0][wl + 4], r0c = sd[0][wl + 5];
  float r1a = sd[1][wl + 3], r1b = sd[1][wl + 4], r1c = sd[1][wl + 5];
#pragma unroll
  for (int r = 0; r < 16; ++r) {
    const float r2a = sd[r + 2][wl + 3], r2b = sd[r + 2][wl + 4],
                r2c = sd[r + 2][wl + 5];
    float a = bs;
    a = fmaf(r0a, wr[0], a);
    a = fmaf(r0b, wr[1], a);
    a = fmaf(r0c, wr[2], a);
    a = fmaf(r1a, wr[3], a);
    a = fmaf(r1b, wr[4], a);
    a = fmaf(r1c, wr[5], a);
    a = fmaf(r2a, wr[6], a);
    a = fmaf(r2b, wr[7], a);
    a = fmaf(r2c, wr[8], a);
    res[r] = a;
    r0a = r1a; r0b = r1b; r0c = r1c;
    r1a = r2a; r1b = r2b; r1c = r2c;
  }
  if (ch < 192) {
    const int qk = ch / 96, c = ch - qk * 96;
    const int bc = b * 96 + c;
    float ss = 0.f;
#pragma unroll
    for (int r = 0; r < 16; ++r) ss = fmaf(res[r], res[r], ss);
    (qk ? nk_p : nq_p)[(size_t)bc * 4096 + hb * 256 + wl] = ss;
    // 16-h granule layout: [bc][hb16][w][16]
    const size_t tb = (size_t)bc * NHW + (size_t)hb * 4096 + (size_t)wl * 16;
    ushort_t* dh = (qk ? kt_hi : qt_hi) + tb;
    ushort_t* dl = (qk ? kt_lo : qt_lo) + tb;
#pragma unroll
    for (int j4 = 0; j4 < 2; ++j4) {
      uint4 H, L;
      unsigned* ph = (unsigned*)&H;
      unsigned* pl = (unsigned*)&L;
#pragma unroll
      for (int e = 0; e < 4; ++e) {
        const float f0 = res[j4 * 8 + 2 * e], f1 = res[j4 * 8 + 2 * e + 1];
        const ushort_t hh0 = f2bf(f0), hh1 = f2bf(f1);
        ph[e] = (unsigned)hh0 | ((unsigned)hh1 << 16);
        pl[e] = (unsigned)f2bf(f0 - bf2f(hh0)) |
                ((unsigned)f2bf(f1 - bf2f(hh1)) << 16);
      }
      *(uint4*)(dh + j4 * 8) = H;
      *(uint4*)(dl + j4 * 8) = L;
    }
  } else {
    const int bc = b * 96 + (ch - 192);
    const int wb = wl >> 5, wsub = wl & 31;
    unsigned* dp = v_pk + (size_t)bc * NHW + wb * 8192 + wsub;
#pragma unroll
    for (int r = 0; r < 16; ++r) {
      const float f = res[r];
      const ushort_t hh = f2bf(f);
      dp[(h0 + r) * 32] = (unsigned)hh | ((unsigned)f2bf(f - bf2f(hh)) << 16);
    }
  }
}

// ---------------- attn: S = QT*K (split-bf16 MFMA) * iq*ik*temp,
// col-softmax over w, P -> pt tiled [bc][wb][v][32w] split bf16 ----
__global__ __launch_bounds__(256, 3) void k_attn_mfma(
    const ushort_t* __restrict__ qt_hi, const ushort_t* __restrict__ qt_lo,
    const ushort_t* __restrict__ kt_hi, const ushort_t* __restrict__ kt_lo,
    const float* __restrict__ nq_p, const float* __restrict__ nk_p,
    const float* __restrict__ temp, ushort_t* __restrict__ pt_hi,
    ushort_t* __restrict__ pt_lo) {
  __shared__ __align__(16) char smem[52480];
  ushort_t* qh = (ushort_t*)smem;
  ushort_t* ql = (ushort_t*)(smem + 20480);
  ushort_t* kh = (ushort_t*)(smem + 40960);
  ushort_t* kl = (ushort_t*)(smem + 46080);
  float* red = (float*)(smem + 51200);
  float* iqs = red;
  float* iks = (float*)(smem + 52224);
  ushort_t* pts = (ushort_t*)smem;

  const int t = threadIdx.x;
  const int lane = t & 63;
  const int wid = t >> 6;
  const int bid = blockIdx.x;
  const int pxb = gridDim.x >> 5;
  const int bc = (bid & 7) * pxb + (bid >> 5);
  const int v0 = ((bid >> 3) & 3) * 64;
  const size_t base_q = (size_t)bc * NHW;
  const size_t base_k = (size_t)bc * NHW;

  f32x4 acc[4][4];
#pragma unroll
  for (int mt = 0; mt < 4; ++mt)
#pragma unroll
    for (int nt = 0; nt < 4; ++nt) acc[mt][nt] = (f32x4){0.f, 0.f, 0.f, 0.f};

  for (int hb = 0; hb < 8; ++hb) {
    {
      // Q: two 16-h granules -> qh row [t][32h]
      const ushort_t* g0 = qt_hi + base_q + (size_t)(2 * hb) * 4096 + t * 16;
      const ushort_t* g1 = g0 + 4096;
      const ushort_t* gl0 = qt_lo + base_q + (size_t)(2 * hb) * 4096 + t * 16;
      const ushort_t* gl1 = gl0 + 4096;
      uint4* dh = (uint4*)(qh + t * 40);
      uint4* dl = (uint4*)(ql + t * 40);
      dh[0] = *(const uint4*)(g0);
      dh[1] = *(const uint4*)(g0 + 8);
      dh[2] = *(const uint4*)(g1);
      dh[3] = *(const uint4*)(g1 + 8);
      dl[0] = *(const uint4*)(gl0);
      dl[1] = *(const uint4*)(gl0 + 8);
      dl[2] = *(const uint4*)(gl1);
      dl[3] = *(const uint4*)(gl1 + 8);
      if (t < 64) {
        const ushort_t* k0 =
            kt_hi + base_k + (size_t)(2 * hb) * 4096 + (size_t)(v0 + t) * 16;
        const ushort_t* k1 = k0 + 4096;
        uint4* dk = (uint4*)(kh + t * 40);
        dk[0] = *(const uint4*)(k0);
        dk[1] = *(const uint4*)(k0 + 8);
        dk[2] = *(const uint4*)(k1);
        dk[3] = *(const uint4*)(k1 + 8);
      } else if (t < 128) {
        const int r = t - 64;
        const ushort_t* k0 =
            kt_lo + base_k + (size_t)(2 * hb) * 4096 + (size_t)(v0 + r) * 16;
        const ushort_t* k1 = k0 + 4096;
        uint4* dk = (uint4*)(kl + r * 40);
        dk[0] = *(const uint4*)(k0);
        dk[1] = *(const uint4*)(k0 + 8);
        dk[2] = *(const uint4*)(k1);
        dk[3] = *(const uint4*)(k1 + 8);
      }
    }
    __syncthreads();
    bf16x8 aH[4], aL[4];
#pragma unroll
    for (int mt = 0; mt < 4; ++mt) {
      const int off = (wid * 64 + mt * 16 + (lane & 15)) * 40 + (lane >> 4) * 8;
      aH[mt] = *(const bf16x8*)(qh + off);
      aL[mt] = *(const bf16x8*)(ql + off);
    }
#pragma unroll
    for (int nt = 0; nt < 4; ++nt) {
      const int off = (nt * 16 + (lane & 15)) * 40 + (lane >> 4) * 8;
      const bf16x8 bH = *(const bf16x8*)(kh + off);
      const bf16x8 bL = *(const bf16x8*)(kl + off);
#pragma unroll
      for (int mt = 0; mt < 4; ++mt) {
        acc[mt][nt] = __builtin_amdgcn_mfma_f32_16x16x32_bf16(aH[mt], bH, acc[mt][nt], 0, 0, 0);
        acc[mt][nt] = __builtin_amdgcn_mfma_f32_16x16x32_bf16(aH[mt], bL, acc[mt][nt], 0, 0, 0);
        acc[mt][nt] = __builtin_amdgcn_mfma_f32_16x16x32_bf16(aL[mt], bH, acc[mt][nt], 0, 0, 0);
      }
    }
    __syncthreads();
  }

  {
    float s8 = 0.f;
    const float* np = nq_p + (size_t)bc * 4096 + t;
#pragma unroll
    for (int hb = 0; hb < 16; ++hb) s8 += np[hb * 256];
    iqs[t] = 1.f / fmaxf(sqrtf(s8), 1e-12f);
    if (t < 64) {
      float sk8 = 0.f;
      const float* nk = nk_p + (size_t)bc * 4096 + v0 + t;
#pragma unroll
      for (int hb = 0; hb < 16; ++hb) sk8 += nk[hb * 256];
      iks[t] = temp[bc % NC] / fmaxf(sqrtf(sk8), 1e-12f);
    }
  }
  __syncthreads();
#pragma unroll
  for (int mt = 0; mt < 4; ++mt) {
    float iq4[4];
#pragma unroll
    for (int r = 0; r < 4; ++r)
      iq4[r] = iqs[wid * 64 + mt * 16 + (lane >> 4) * 4 + r];
#pragma unroll
    for (int nt = 0; nt < 4; ++nt) {
      const float ikv = iks[nt * 16 + (lane & 15)];
#pragma unroll
      for (int r = 0; r < 4; ++r) acc[mt][nt][r] *= iq4[r] * ikv;
    }
  }
  __syncthreads();

  float Mv[4], Sv[4];
#pragma unroll
  for (int nt = 0; nt < 4; ++nt) {
    float m = -3.4e38f;
#pragma unroll
    for (int mt = 0; mt < 4; ++mt)
#pragma unroll
      for (int r = 0; r < 4; ++r) m = fmaxf(m, acc[mt][nt][r]);
    m = fmaxf(m, __shfl_xor(m, 16));
    m = fmaxf(m, __shfl_xor(m, 32));
    if (lane < 16) red[wid * 64 + nt * 16 + lane] = m;
  }
  __syncthreads();
#pragma unroll
  for (int nt = 0; nt < 4; ++nt) {
    const int vl = nt * 16 + (lane & 15);
    Mv[nt] = fmaxf(fmaxf(red[vl], red[64 + vl]),
                   fmaxf(red[128 + vl], red[192 + vl]));
  }
  __syncthreads();
#pragma unroll
  for (int nt = 0; nt < 4; ++nt) {
    float s = 0.f;
#pragma unroll
    for (int mt = 0; mt < 4; ++mt)
#pragma unroll
      for (int r = 0; r < 4; ++r) {
        const float p = __expf(acc[mt][nt][r] - Mv[nt]);
        acc[mt][nt][r] = p;
        s += p;
      }
    s += __shfl_xor(s, 16);
    s += __shfl_xor(s, 32);
    if (lane < 16) red[wid * 64 + nt * 16 + lane] = s;
  }
  __syncthreads();
#pragma unroll
  for (int nt = 0; nt < 4; ++nt) {
    const int vl = nt * 16 + (lane & 15);
    Sv[nt] = 1.f / (red[vl] + red[64 + vl] + red[128 + vl] + red[192 + vl]);
  }
#pragma unroll
  for (int nt = 0; nt < 4; ++nt)
#pragma unroll
    for (int mt = 0; mt < 4; ++mt)
#pragma unroll
      for (int r = 0; r < 4; ++r) acc[mt][nt][r] *= Sv[nt];
  __syncthreads();

  for (int pass = 0; pass < 2; ++pass) {
#pragma unroll
    for (int nt = 0; nt < 4; ++nt)
#pragma unroll
      for (int mt = 0; mt < 4; ++mt) {
        ushort_t pk[4];
#pragma unroll
        for (int r = 0; r < 4; ++r) {
          const float p = acc[mt][nt][r];
          const ushort_t hi = f2bf(p);
          pk[r] = pass == 0 ? hi : f2bf(p - bf2f(hi));
        }
        const int v = nt * 16 + (lane & 15);
        const int wb2 = wid * 64 + mt * 16 + ((lane >> 4) << 2);
        *(ushort4*)(pts + v * 264 + wb2) =
            make_ushort4(pk[0], pk[1], pk[2], pk[3]);
      }
    __syncthreads();
    ushort_t* dst = pass == 0 ? pt_hi : pt_lo;
#pragma unroll
    for (int i = 0; i < 2; ++i) {
      const int cid = t + (i << 8);
      const int wb = cid >> 6, v = cid & 63;
      const ushort_t* sp = pts + v * 264 + wb * 32;
      ushort_t* d = dst + (size_t)bc * NHW + (size_t)wb * 8192 +
                    (size_t)(v0 + v) * 32;
#pragma unroll
      for (int j = 0; j < 4; ++j)
        *(uint4*)(d + j * 8) = *(const uint4*)(sp + j * 8);
    }
    __syncthreads();
  }
}

// ---------------- out[h][v] = sum_w V[h][w] * P[w][v], split-bf16 MFMA ----
// v2: LDS-staged coalesced epilogue (est aliases staging region).
__global__ __launch_bounds__(256, 3) void k_av_mfma(
    const unsigned* __restrict__ v_pk, const ushort_t* __restrict__ pt_hi,
    const ushort_t* __restrict__ pt_lo, float* __restrict__ aout) {
  __shared__ __align__(16) char smem[40960];
  ushort_t* vh = (ushort_t*)smem;             // [128][40]
  ushort_t* vl = (ushort_t*)(smem + 10240);   // [128][40]
  ushort_t* ph = (ushort_t*)(smem + 20480);   // [128][40]
  ushort_t* pl = (ushort_t*)(smem + 30720);   // [128][40]
  float* est = (float*)smem;                  // [64][132] = 33792 B (alias)
  const int t = threadIdx.x;
  const int lane = t & 63;
  const int wid = t >> 6;
  const int bid = blockIdx.x;
  const int pxb = gridDim.x >> 5;
  const int bc = (bid & 7) * pxb + (bid >> 5);
  const int tile = (bid >> 3) & 3;
  const int h0 = (tile >> 1) * 128, v0 = (tile & 1) * 128;
  const int wh = wid >> 1, wv = wid & 1;

  f32x4 acc[4][4];
#pragma unroll
  for (int mt = 0; mt < 4; ++mt)
#pragma unroll
    for (int nt = 0; nt < 4; ++nt) acc[mt][nt] = (f32x4){0.f, 0.f, 0.f, 0.f};

  for (int wb = 0; wb < 8; ++wb) {
#pragma unroll
    for (int i = 0; i < 4; ++i) {
      const int id = t + (i << 8);
      const int row = id >> 3, q = id & 7;
      const uint4 pk = *(const uint4*)(v_pk + (size_t)bc * NHW + wb * 8192 +
                                       (size_t)(h0 + row) * 32 + q * 4);
      const ushort4 hi4 =
          make_ushort4((ushort_t)(pk.x & 0xffff), (ushort_t)(pk.y & 0xffff),
                       (ushort_t)(pk.z & 0xffff), (ushort_t)(pk.w & 0xffff));
      const ushort4 lo4 =
          make_ushort4((ushort_t)(pk.x >> 16), (ushort_t)(pk.y >> 16),
                       (ushort_t)(pk.z >> 16), (ushort_t)(pk.w >> 16));
      *(ushort4*)(vh + row * 40 + q * 4) = hi4;
      *(ushort4*)(vl + row * 40 + q * 4) = lo4;
    }
#pragma unroll
    for (int i = 0; i < 4; ++i) {
      const int id = t + (i << 8);
      const int arr = id >> 9, rem = id & 511;
      const int row = rem >> 2, q = rem & 3;
      const ushort_t* g = (arr ? pt_lo : pt_hi) + (size_t)bc * NHW +
                          wb * 8192 + (size_t)(v0 + row) * 32 + q * 8;
      ushort_t* d = (arr ? pl : ph) + row * 40 + q * 8;
      *(uint4*)d = *(const uint4*)g;
    }
    __syncthreads();
    bf16x8 aH[4], aL[4];
#pragma unroll
    for (int mt = 0; mt < 4; ++mt) {
      const int off = (wh * 64 + mt * 16 + (lane & 15)) * 40 + (lane >> 4) * 8;
      aH[mt] = *(const bf16x8*)(vh + off);
      aL[mt] = *(const bf16x8*)(vl + off);
    }
#pragma unroll
    for (int nt = 0; nt < 4; ++nt) {
      const int off = (wv * 64 + nt * 16 + (lane & 15)) * 40 + (lane >> 4) * 8;
      const bf16x8 bH = *(const bf16x8*)(ph + off);
      const bf16x8 bL = *(const bf16x8*)(pl + off);
#pragma unroll
      for (int mt = 0; mt < 4; ++mt) {
        acc[mt][nt] = __builtin_amdgcn_mfma_f32_16x16x32_bf16(aH[mt], bH, acc[mt][nt], 0, 0, 0);
        acc[mt][nt] = __builtin_amdgcn_mfma_f32_16x16x32_bf16(aH[mt], bL, acc[mt][nt], 0, 0, 0);
        acc[mt][nt] = __builtin_amdgcn_mfma_f32_16x16x32_bf16(aL[mt], bH, acc[mt][nt], 0, 0, 0);
      }
    }
    __syncthreads();
  }

  // LDS-staged epilogue: two 64-row chunks, contiguous float4 row writes
#pragma unroll 1
  for (int c = 0; c < 2; ++c) {
    if (c) __syncthreads();  // prior chunk's est reads done
    if (wh == c) {
#pragma unroll
      for (int mt = 0; mt < 4; ++mt) {
        const int row = mt * 16 + (lane >> 4) * 4;
#pragma unroll
        for (int nt = 0; nt < 4; ++nt) {
          const int col = wv * 64 + nt * 16 + (lane & 15);
#pragma unroll
          for (int r = 0; r < 4; ++r) est[(row + r) * 132 + col] = acc[mt][nt][r];
        }
      }
    }
    __syncthreads();
    float* ob = aout + (size_t)bc * NHW + (size_t)(h0 + c * 64) * NW + v0;
#pragma unroll
    for (int i = 0; i < 8; ++i) {
      const int idx = t + 256 * i;  // 2048 float4 = 64 rows x 32
      const int row = idx >> 5, c4 = (idx & 31) << 2;
      *(float4*)(ob + (size_t)row * NW + c4) = *(const float4*)&est[row * 132 + c4];
    }
  }
}

extern "C" void kernel_launch(void* const* d_in, const int* in_sizes, int n_in,
                              void* d_out, int out_size, void* d_ws,
                              size_t ws_size, hipStream_t stream) {
  const float* x = (const float*)d_in[0];
  const float* qkv_w = (const float*)d_in[1];
  const float* qkv_b = (const float*)d_in[2];
  const float* dw_w = (const float*)d_in[3];
  const float* dw_b = (const float*)d_in[4];
  const float* temp = (const float*)d_in[5];
  const float* proj_w = (const float*)d_in[6];
  const float* proj_b = (const float*)d_in[7];
  float* out = (float*)d_out;

  auto need = [](int nb) -> size_t {
    return (size_t)nb * 154140672ull + 147456ull;
  };
  int nb = 1;
  if (need(4) <= ws_size) nb = 4;
  else if (need(2) <= ws_size) nb = 2;

  char* base = (char*)d_ws;
  const size_t QKV_T = (size_t)nb * 75497472ull;  // region reserved; packed uses 1/2
  const size_t HALF = (size_t)nb * 12582912ull;
  const size_t NQB = (size_t)nb * 1572864ull;
  unsigned* qkv_tiled = (unsigned*)base;  // packed u32, nb*37748736 bytes
  ushort_t* pt_hi = (ushort_t*)base;      // alias (qkv dead after dw3)
  ushort_t* pt_lo = (ushort_t*)(base + HALF);
  float* aout = (float*)(base + 2 * HALF);
  char* p = base + QKV_T;
  ushort_t* qt_hi = (ushort_t*)p; p += HALF;
  ushort_t* qt_lo = (ushort_t*)p; p += HALF;
  ushort_t* kt_hi = (ushort_t*)p; p += HALF;
  ushort_t* kt_lo = (ushort_t*)p; p += HALF;
  unsigned* v_pk = (unsigned*)p; p += 2 * HALF;
  float* nq_p = (float*)p; p += NQB;
  float* nk_p = (float*)p; p += NQB;
  ushort_t* wq_hi = (ushort_t*)p; p += 55296;
  ushort_t* wq_lo = (ushort_t*)p; p += 55296;
  ushort_t* wp_hi = (ushort_t*)p; p += 18432;
  ushort_t* wp_lo = (ushort_t*)p;

  k_wprep<<<dim3(144), 256, 0, stream>>>(qkv_w, proj_w, wq_hi, wq_lo, wp_hi, wp_lo);

  const int BC = nb * NC;
  for (int b0 = 0; b0 < 4; b0 += nb) {
    const float* xb = x + (size_t)b0 * NC * NHW;
    float* outb = out + (size_t)b0 * NC * NHW;
    k_conv<NC3, true><<<dim3(1024, nb), 256, 0, stream>>>(
        xb, wq_hi, wq_lo, qkv_b, (float*)qkv_tiled);
    k_dw3<<<dim3(16, nb * NC3), 256, 0, stream>>>(
        qkv_tiled, dw_w, dw_b, qt_hi, qt_lo, kt_hi, kt_lo, v_pk, nq_p, nk_p);
    k_attn_mfma<<<dim3(BC * 4), 256, 0, stream>>>(
        qt_hi, qt_lo, kt_hi, kt_lo, nq_p, nk_p, temp, pt_hi, pt_lo);
    k_av_mfma<<<dim3(BC * 4), 256, 0, stream>>>(v_pk, pt_hi, pt_lo, aout);
    k_conv<NC, false><<<dim3(1024, nb), 256, 0, stream>>>(
        aout, wp_hi, wp_lo, proj_b, outb);
  }
}

// Round 19
// 461.637 us; speedup vs baseline: 1.2158x; 1.1271x over previous
//
#include <hip/hip_runtime.h>

#define NC 96
#define NC3 288
#define NH 256
#define NW 256
#define NHW 65536

typedef unsigned short ushort_t;
typedef __attribute__((ext_vector_type(8))) short bf16x8;
typedef __attribute__((ext_vector_type(4))) float f32x4;

__device__ __forceinline__ ushort_t f2bf(float x) {
  unsigned u = __float_as_uint(x);
  u += 0x7fffu + ((u >> 16) & 1u);
  return (ushort_t)(u >> 16);
}
__device__ __forceinline__ float bf2f(ushort_t h) {
  return __uint_as_float((unsigned)h << 16);
}
// pack fp32 -> u32: low16 = bf16(hi), high16 = bf16(residual)
__device__ __forceinline__ unsigned pack_split(float f) {
  unsigned u = __float_as_uint(f);
  unsigned ur = u + (0x7fffu + ((u >> 16) & 1u));
  const float rem = f - __uint_as_float(ur & 0xffff0000u);
  unsigned v = __float_as_uint(rem);
  v += 0x7fffu + ((v >> 16) & 1u);
  return (ur >> 16) | (v & 0xffff0000u);
}
// unpack u32 -> fp32 (hi + lo)
__device__ __forceinline__ float upk(unsigned u) {
  return __uint_as_float(u << 16) + __uint_as_float(u & 0xffff0000u);
}

// ---------------- weight prep: split-bf16 in MFMA FRAGMENT ORDER ----------
// qkv: [step=ocg*3+kk][m][lane][8]  (oc = ocg*96+m*16+(lane&15),
//                                   c = kk*32+(lane>>4)*8+e)
// proj: same with ocg=0 (step=kk).
__global__ __launch_bounds__(256) void k_wprep(
    const float* __restrict__ qkv_w, const float* __restrict__ proj_w,
    ushort_t* __restrict__ wq_hi, ushort_t* __restrict__ wq_lo,
    ushort_t* __restrict__ wp_hi, ushort_t* __restrict__ wp_lo) {
  const int id = blockIdx.x * 256 + threadIdx.x;
  if (id < NC3 * NC) {
    const int e = id & 7, lane = (id >> 3) & 63, fm = id >> 9;
    const int m = fm % 6, kk = (fm / 6) % 3, ocg = fm / 18;
    const int oc = ocg * 96 + m * 16 + (lane & 15);
    const int c = kk * 32 + (lane >> 4) * 8 + e;
    const float v = qkv_w[oc * NC + c];
    const ushort_t h = f2bf(v);
    wq_hi[id] = h;
    wq_lo[id] = f2bf(v - bf2f(h));
  } else {
    const int j = id - NC3 * NC;  // < NC*NC
    const int e = j & 7, lane = (j >> 3) & 63, fm = j >> 9;
    const int m = fm % 6, kk = fm / 6;
    const int oc = m * 16 + (lane & 15);
    const int c = kk * 32 + (lane >> 4) * 8 + e;
    const float v = proj_w[oc * NC + c];
    const ushort_t h = f2bf(v);
    wp_hi[j] = h;
    wp_lo[j] = f2bf(v - bf2f(h));
  }
}

// ---------------- 1x1 conv: fused transpose + split-bf16 MFMA GEMM ----------
// v5: fragment-ordered weights -> each wave weight load is 1024B dense
// (4 lines/quarter-wave vs 16 with the strided layout).
// TILED: out = packed u32 [(b*1024+sblk)][OUTC][64]; else fp32 [b][o][s].
template <int OUTC, bool TILED>
__global__ __launch_bounds__(256, 4) void k_conv(
    const float* __restrict__ in, const ushort_t* __restrict__ w_hi,
    const ushort_t* __restrict__ w_lo, const float* __restrict__ bias,
    float* __restrict__ out) {
  __shared__ __align__(16) char smem[39936];
  ushort_t* xh = (ushort_t*)smem;            // [64][104]
  ushort_t* xl = (ushort_t*)(smem + 13312);  // [64][104]
  float* xt48 = (float*)(smem + 26624);      // [48][68]
  float* est = (float*)smem;                 // [96][66] epilogue stage (alias)
  const int t = threadIdx.x;
  const int bz = blockIdx.y;
  const int sblk = blockIdx.x;
  const int s0 = sblk * 64;
  const float* xb = in + (size_t)bz * NC * NHW + s0;

  const int lane = t & 63, wave = t >> 6;
  const int ln15 = lane & 15;
  const int akof = (lane >> 4) * 8;

  // two-pass transpose+split-pack: 48 channels per pass
#pragma unroll 1
  for (int half = 0; half < 2; ++half) {
    if (half) __syncthreads();  // pack reads of pass 0 complete
#pragma unroll
    for (int i = 0; i < 3; ++i) {
      const int idx = t + 256 * i;  // 768 float4 = 48 rows x 16
      const int row = idx >> 4, c4 = (idx & 15) << 2;
      *(float4*)&xt48[row * 68 + c4] =
          *(const float4*)&xb[(size_t)(half * 48 + row) * NHW + c4];
    }
    __syncthreads();
    {
      const int s = t & 63, cg = t >> 6;
#pragma unroll
      for (int i = 0; i < 6; ++i) {
        const int cl = cg * 12 + i * 2;
        const float f0 = xt48[cl * 68 + s], f1 = xt48[(cl + 1) * 68 + s];
        const ushort_t h0 = f2bf(f0), h1 = f2bf(f1);
        const ushort_t l0 = f2bf(f0 - bf2f(h0)), l1 = f2bf(f1 - bf2f(h1));
        const int c = half * 48 + cl;
        *(unsigned*)&xh[s * 104 + c] = (unsigned)h0 | ((unsigned)h1 << 16);
        *(unsigned*)&xl[s * 104 + c] = (unsigned)l0 | ((unsigned)l1 << 16);
      }
    }
  }
  __syncthreads();
  bf16x8 bH[3], bL[3];
  {
    const int srow = wave * 16 + ln15;
#pragma unroll
    for (int kk = 0; kk < 3; ++kk) {
      bH[kk] = *(const bf16x8*)&xh[srow * 104 + kk * 32 + akof];
      bL[kk] = *(const bf16x8*)&xl[srow * 104 + kk * 32 + akof];
    }
  }

  constexpr int S = 3 * (OUTC / 96);
  const int sl = wave * 16 + ln15;
  f32x4 acc[6];
#pragma unroll
  for (int step = 0; step < S; ++step) {
    const int ocg = step / 3, kk = step % 3;
    if (kk == 0) {
#pragma unroll
      for (int m = 0; m < 6; ++m) acc[m] = (f32x4){0.f, 0.f, 0.f, 0.f};
    }
#pragma unroll
    for (int m = 0; m < 6; ++m) {
      const size_t wi = (((size_t)step * 6 + m) * 64 + lane) * 8;
      const bf16x8 aH = *(const bf16x8*)(w_hi + wi);
      const bf16x8 aL = *(const bf16x8*)(w_lo + wi);
      acc[m] = __builtin_amdgcn_mfma_f32_16x16x32_bf16(aH, bH[kk], acc[m], 0, 0, 0);
      acc[m] = __builtin_amdgcn_mfma_f32_16x16x32_bf16(aH, bL[kk], acc[m], 0, 0, 0);
      acc[m] = __builtin_amdgcn_mfma_f32_16x16x32_bf16(aL, bH[kk], acc[m], 0, 0, 0);
    }
    // epilogue after the last kk of this oc-group: LDS-staged coalesced store
    if (kk == 2) {
      __syncthreads();  // xh/xl frag reads done (ocg0) / prior est reads done
#pragma unroll
      for (int m = 0; m < 6; ++m) {
        const int o2 = m * 16 + (lane >> 4) * 4;
#pragma unroll
        for (int r = 0; r < 4; ++r) est[(o2 + r) * 66 + sl] = acc[m][r];
      }
      __syncthreads();
      if (TILED) {
        unsigned* ob = (unsigned*)out +
                       ((size_t)(bz * 1024 + sblk)) * OUTC * 64 +
                       (size_t)ocg * 96 * 64;
#pragma unroll
        for (int j = 0; j < 6; ++j) {
          const int idx = t + 256 * j;
          const int row = idx >> 4, c4 = (idx & 15) << 2;
          const float bs = bias[ocg * 96 + row];
          uint4 pkv;
          pkv.x = pack_split(est[row * 66 + c4 + 0] + bs);
          pkv.y = pack_split(est[row * 66 + c4 + 1] + bs);
          pkv.z = pack_split(est[row * 66 + c4 + 2] + bs);
          pkv.w = pack_split(est[row * 66 + c4 + 3] + bs);
          *(uint4*)(ob + (size_t)row * 64 + c4) = pkv;
        }
      } else {
        float* ob = out + (size_t)bz * OUTC * NHW + s0;
#pragma unroll
        for (int j = 0; j < 6; ++j) {
          const int idx = t + 256 * j;
          const int row = idx >> 4, c4 = (idx & 15) << 2;
          const float bs = bias[ocg * 96 + row];
          const float4 v = make_float4(
              est[row * 66 + c4] + bs, est[row * 66 + c4 + 1] + bs,
              est[row * 66 + c4 + 2] + bs, est[row * 66 + c4 + 3] + bs);
          *(float4*)(ob + (size_t)(ocg * 96 + row) * NHW + c4) = v;
        }
      }
    }
  }
}

// ---------------- depthwise 3x3 + layout emit + norm partials ----------------
// q/k -> qt/kt in 16-h granules [bc][hb16][w][16h] (fully coalesced stores)
// v   -> v_pk  [bc][wb][h][32w] u32 (hi|lo<<16)
__global__ __launch_bounds__(256, 8) void k_dw3(
    const unsigned* __restrict__ qkvt, const float* __restrict__ w,
    const float* __restrict__ bias, ushort_t* __restrict__ qt_hi,
    ushort_t* __restrict__ qt_lo, ushort_t* __restrict__ kt_hi,
    ushort_t* __restrict__ kt_lo, unsigned* __restrict__ v_pk,
    float* __restrict__ nq_p, float* __restrict__ nk_p) {
  __shared__ float sd[18][264];
  const int t = threadIdx.x;
  const int hb = blockIdx.x;
  const int bcc = blockIdx.y;
  const int b = bcc / NC3, ch = bcc % NC3;
  const int h0 = hb * 16;
  const unsigned* src = qkvt + (size_t)b * 1024 * NC3 * 64 + (size_t)ch * 64;
#pragma unroll
  for (int i = 0; i < 5; ++i) {
    const int idx = t + 256 * i;
    if (idx < 18 * 64) {
      const int r = idx >> 6, j = idx & 63;
      const int gh = h0 + r - 1;
      float4 v = make_float4(0.f, 0.f, 0.f, 0.f);
      if (gh >= 0 && gh < 256) {
        const int gw = 4 * j;
        const uint4 pv = *(const uint4*)&src[(size_t)(gh * 4 + (gw >> 6)) *
                                                 (NC3 * 64) +
                                             (gw & 63)];
        v = make_float4(upk(pv.x), upk(pv.y), upk(pv.z), upk(pv.w));
      }
      *(float4*)&sd[r][4 + 4 * j] = v;
    }
  }
  if (t < 36) {
    const int r = t >> 1;
    sd[r][(t & 1) ? 260 : 3] = 0.f;
  }
  __syncthreads();
  float wr[9];
#pragma unroll
  for (int k = 0; k < 9; ++k) wr[k] = w[ch * 9 + k];
  const float bs = bias[ch];
  const int wl = t;
  float res[16];
  float r0a = sd[0][wl + 3], r0b = sd[0][wl + 4], r0c = sd[0][wl + 5];
  float r1a = sd[1][wl + 3], r1b = sd[1][wl + 4], r1c = sd[1][wl + 5];
#pragma unroll
  for (int r = 0; r < 16; ++r) {
    const float r2a = sd[r + 2][wl + 3], r2b = sd[r + 2][wl + 4],
                r2c = sd[r + 2][wl + 5];
    float a = bs;
    a = fmaf(r0a, wr[0], a);
    a = fmaf(r0b, wr[1], a);
    a = fmaf(r0c, wr[2], a);
    a = fmaf(r1a, wr[3], a);
    a = fmaf(r1b, wr[4], a);
    a = fmaf(r1c, wr[5], a);
    a = fmaf(r2a, wr[6], a);
    a = fmaf(r2b, wr[7], a);
    a = fmaf(r2c, wr[8], a);
    res[r] = a;
    r0a = r1a; r0b = r1b; r0c = r1c;
    r1a = r2a; r1b = r2b; r1c = r2c;
  }
  if (ch < 192) {
    const int qk = ch / 96, c = ch - qk * 96;
    const int bc = b * 96 + c;
    float ss = 0.f;
#pragma unroll
    for (int r = 0; r < 16; ++r) ss = fmaf(res[r], res[r], ss);
    (qk ? nk_p : nq_p)[(size_t)bc * 4096 + hb * 256 + wl] = ss;
    // 16-h granule layout: [bc][hb16][w][16]
    const size_t tb = (size_t)bc * NHW + (size_t)hb * 4096 + (size_t)wl * 16;
    ushort_t* dh = (qk ? kt_hi : qt_hi) + tb;
    ushort_t* dl = (qk ? kt_lo : qt_lo) + tb;
#pragma unroll
    for (int j4 = 0; j4 < 2; ++j4) {
      uint4 H, L;
      unsigned* ph = (unsigned*)&H;
      unsigned* pl = (unsigned*)&L;
#pragma unroll
      for (int e = 0; e < 4; ++e) {
        const float f0 = res[j4 * 8 + 2 * e], f1 = res[j4 * 8 + 2 * e + 1];
        const ushort_t hh0 = f2bf(f0), hh1 = f2bf(f1);
        ph[e] = (unsigned)hh0 | ((unsigned)hh1 << 16);
        pl[e] = (unsigned)f2bf(f0 - bf2f(hh0)) |
                ((unsigned)f2bf(f1 - bf2f(hh1)) << 16);
      }
      *(uint4*)(dh + j4 * 8) = H;
      *(uint4*)(dl + j4 * 8) = L;
    }
  } else {
    const int bc = b * 96 + (ch - 192);
    const int wb = wl >> 5, wsub = wl & 31;
    unsigned* dp = v_pk + (size_t)bc * NHW + wb * 8192 + wsub;
#pragma unroll
    for (int r = 0; r < 16; ++r) {
      const float f = res[r];
      const ushort_t hh = f2bf(f);
      dp[(h0 + r) * 32] = (unsigned)hh | ((unsigned)f2bf(f - bf2f(hh)) << 16);
    }
  }
}

// ---------------- attn: S = QT*K (split-bf16 MFMA) * iq*ik*temp,
// col-softmax over w, P -> pt tiled [bc][wb][v][32w] split bf16 ----
__global__ __launch_bounds__(256, 3) void k_attn_mfma(
    const ushort_t* __restrict__ qt_hi, const ushort_t* __restrict__ qt_lo,
    const ushort_t* __restrict__ kt_hi, const ushort_t* __restrict__ kt_lo,
    const float* __restrict__ nq_p, const float* __restrict__ nk_p,
    const float* __restrict__ temp, ushort_t* __restrict__ pt_hi,
    ushort_t* __restrict__ pt_lo) {
  __shared__ __align__(16) char smem[52480];
  ushort_t* qh = (ushort_t*)smem;
  ushort_t* ql = (ushort_t*)(smem + 20480);
  ushort_t* kh = (ushort_t*)(smem + 40960);
  ushort_t* kl = (ushort_t*)(smem + 46080);
  float* red = (float*)(smem + 51200);
  float* iqs = red;
  float* iks = (float*)(smem + 52224);
  ushort_t* pts = (ushort_t*)smem;

  const int t = threadIdx.x;
  const int lane = t & 63;
  const int wid = t >> 6;
  const int bid = blockIdx.x;
  const int pxb = gridDim.x >> 5;
  const int bc = (bid & 7) * pxb + (bid >> 5);
  const int v0 = ((bid >> 3) & 3) * 64;
  const size_t base_q = (size_t)bc * NHW;
  const size_t base_k = (size_t)bc * NHW;

  f32x4 acc[4][4];
#pragma unroll
  for (int mt = 0; mt < 4; ++mt)
#pragma unroll
    for (int nt = 0; nt < 4; ++nt) acc[mt][nt] = (f32x4){0.f, 0.f, 0.f, 0.f};

  for (int hb = 0; hb < 8; ++hb) {
    {
      // Q: two 16-h granules -> qh row [t][32h]
      const ushort_t* g0 = qt_hi + base_q + (size_t)(2 * hb) * 4096 + t * 16;
      const ushort_t* g1 = g0 + 4096;
      const ushort_t* gl0 = qt_lo + base_q + (size_t)(2 * hb) * 4096 + t * 16;
      const ushort_t* gl1 = gl0 + 4096;
      uint4* dh = (uint4*)(qh + t * 40);
      uint4* dl = (uint4*)(ql + t * 40);
      dh[0] = *(const uint4*)(g0);
      dh[1] = *(const uint4*)(g0 + 8);
      dh[2] = *(const uint4*)(g1);
      dh[3] = *(const uint4*)(g1 + 8);
      dl[0] = *(const uint4*)(gl0);
      dl[1] = *(const uint4*)(gl0 + 8);
      dl[2] = *(const uint4*)(gl1);
      dl[3] = *(const uint4*)(gl1 + 8);
      if (t < 64) {
        const ushort_t* k0 =
            kt_hi + base_k + (size_t)(2 * hb) * 4096 + (size_t)(v0 + t) * 16;
        const ushort_t* k1 = k0 + 4096;
        uint4* dk = (uint4*)(kh + t * 40);
        dk[0] = *(const uint4*)(k0);
        dk[1] = *(const uint4*)(k0 + 8);
        dk[2] = *(const uint4*)(k1);
        dk[3] = *(const uint4*)(k1 + 8);
      } else if (t < 128) {
        const int r = t - 64;
        const ushort_t* k0 =
            kt_lo + base_k + (size_t)(2 * hb) * 4096 + (size_t)(v0 + r) * 16;
        const ushort_t* k1 = k0 + 4096;
        uint4* dk = (uint4*)(kl + r * 40);
        dk[0] = *(const uint4*)(k0);
        dk[1] = *(const uint4*)(k0 + 8);
        dk[2] = *(const uint4*)(k1);
        dk[3] = *(const uint4*)(k1 + 8);
      }
    }
    __syncthreads();
    bf16x8 aH[4], aL[4];
#pragma unroll
    for (int mt = 0; mt < 4; ++mt) {
      const int off = (wid * 64 + mt * 16 + (lane & 15)) * 40 + (lane >> 4) * 8;
      aH[mt] = *(const bf16x8*)(qh + off);
      aL[mt] = *(const bf16x8*)(ql + off);
    }
#pragma unroll
    for (int nt = 0; nt < 4; ++nt) {
      const int off = (nt * 16 + (lane & 15)) * 40 + (lane >> 4) * 8;
      const bf16x8 bH = *(const bf16x8*)(kh + off);
      const bf16x8 bL = *(const bf16x8*)(kl + off);
#pragma unroll
      for (int mt = 0; mt < 4; ++mt) {
        acc[mt][nt] = __builtin_amdgcn_mfma_f32_16x16x32_bf16(aH[mt], bH, acc[mt][nt], 0, 0, 0);
        acc[mt][nt] = __builtin_amdgcn_mfma_f32_16x16x32_bf16(aH[mt], bL, acc[mt][nt], 0, 0, 0);
        acc[mt][nt] = __builtin_amdgcn_mfma_f32_16x16x32_bf16(aL[mt], bH, acc[mt][nt], 0, 0, 0);
      }
    }
    __syncthreads();
  }

  {
    float s8 = 0.f;
    const float* np = nq_p + (size_t)bc * 4096 + t;
#pragma unroll
    for (int hb = 0; hb < 16; ++hb) s8 += np[hb * 256];
    iqs[t] = 1.f / fmaxf(sqrtf(s8), 1e-12f);
    if (t < 64) {
      float sk8 = 0.f;
      const float* nk = nk_p + (size_t)bc * 4096 + v0 + t;
#pragma unroll
      for (int hb = 0; hb < 16; ++hb) sk8 += nk[hb * 256];
      iks[t] = temp[bc % NC] / fmaxf(sqrtf(sk8), 1e-12f);
    }
  }
  __syncthreads();
#pragma unroll
  for (int mt = 0; mt < 4; ++mt) {
    float iq4[4];
#pragma unroll
    for (int r = 0; r < 4; ++r)
      iq4[r] = iqs[wid * 64 + mt * 16 + (lane >> 4) * 4 + r];
#pragma unroll
    for (int nt = 0; nt < 4; ++nt) {
      const float ikv = iks[nt * 16 + (lane & 15)];
#pragma unroll
      for (int r = 0; r < 4; ++r) acc[mt][nt][r] *= iq4[r] * ikv;
    }
  }
  __syncthreads();

  float Mv[4], Sv[4];
#pragma unroll
  for (int nt = 0; nt < 4; ++nt) {
    float m = -3.4e38f;
#pragma unroll
    for (int mt = 0; mt < 4; ++mt)
#pragma unroll
      for (int r = 0; r < 4; ++r) m = fmaxf(m, acc[mt][nt][r]);
    m = fmaxf(m, __shfl_xor(m, 16));
    m = fmaxf(m, __shfl_xor(m, 32));
    if (lane < 16) red[wid * 64 + nt * 16 + lane] = m;
  }
  __syncthreads();
#pragma unroll
  for (int nt = 0; nt < 4; ++nt) {
    const int vl = nt * 16 + (lane & 15);
    Mv[nt] = fmaxf(fmaxf(red[vl], red[64 + vl]),
                   fmaxf(red[128 + vl], red[192 + vl]));
  }
  __syncthreads();
#pragma unroll
  for (int nt = 0; nt < 4; ++nt) {
    float s = 0.f;
#pragma unroll
    for (int mt = 0; mt < 4; ++mt)
#pragma unroll
      for (int r = 0; r < 4; ++r) {
        const float p = __expf(acc[mt][nt][r] - Mv[nt]);
        acc[mt][nt][r] = p;
        s += p;
      }
    s += __shfl_xor(s, 16);
    s += __shfl_xor(s, 32);
    if (lane < 16) red[wid * 64 + nt * 16 + lane] = s;
  }
  __syncthreads();
#pragma unroll
  for (int nt = 0; nt < 4; ++nt) {
    const int vl = nt * 16 + (lane & 15);
    Sv[nt] = 1.f / (red[vl] + red[64 + vl] + red[128 + vl] + red[192 + vl]);
  }
#pragma unroll
  for (int nt = 0; nt < 4; ++nt)
#pragma unroll
    for (int mt = 0; mt < 4; ++mt)
#pragma unroll
      for (int r = 0; r < 4; ++r) acc[mt][nt][r] *= Sv[nt];
  __syncthreads();

  for (int pass = 0; pass < 2; ++pass) {
#pragma unroll
    for (int nt = 0; nt < 4; ++nt)
#pragma unroll
      for (int mt = 0; mt < 4; ++mt) {
        ushort_t pk[4];
#pragma unroll
        for (int r = 0; r < 4; ++r) {
          const float p = acc[mt][nt][r];
          const ushort_t hi = f2bf(p);
          pk[r] = pass == 0 ? hi : f2bf(p - bf2f(hi));
        }
        const int v = nt * 16 + (lane & 15);
        const int wb2 = wid * 64 + mt * 16 + ((lane >> 4) << 2);
        *(ushort4*)(pts + v * 264 + wb2) =
            make_ushort4(pk[0], pk[1], pk[2], pk[3]);
      }
    __syncthreads();
    ushort_t* dst = pass == 0 ? pt_hi : pt_lo;
#pragma unroll
    for (int i = 0; i < 2; ++i) {
      const int cid = t + (i << 8);
      const int wb = cid >> 6, v = cid & 63;
      const ushort_t* sp = pts + v * 264 + wb * 32;
      ushort_t* d = dst + (size_t)bc * NHW + (size_t)wb * 8192 +
                    (size_t)(v0 + v) * 32;
#pragma unroll
      for (int j = 0; j < 4; ++j)
        *(uint4*)(d + j * 8) = *(const uint4*)(sp + j * 8);
    }
    __syncthreads();
  }
}

// ---------------- out[h][v] = sum_w V[h][w] * P[w][v], split-bf16 MFMA ----
// v2: LDS-staged coalesced epilogue (est aliases staging region).
__global__ __launch_bounds__(256, 3) void k_av_mfma(
    const unsigned* __restrict__ v_pk, const ushort_t* __restrict__ pt_hi,
    const ushort_t* __restrict__ pt_lo, float* __restrict__ aout) {
  __shared__ __align__(16) char smem[40960];
  ushort_t* vh = (ushort_t*)smem;             // [128][40]
  ushort_t* vl = (ushort_t*)(smem + 10240);   // [128][40]
  ushort_t* ph = (ushort_t*)(smem + 20480);   // [128][40]
  ushort_t* pl = (ushort_t*)(smem + 30720);   // [128][40]
  float* est = (float*)smem;                  // [64][132] = 33792 B (alias)
  const int t = threadIdx.x;
  const int lane = t & 63;
  const int wid = t >> 6;
  const int bid = blockIdx.x;
  const int pxb = gridDim.x >> 5;
  const int bc = (bid & 7) * pxb + (bid >> 5);
  const int tile = (bid >> 3) & 3;
  const int h0 = (tile >> 1) * 128, v0 = (tile & 1) * 128;
  const int wh = wid >> 1, wv = wid & 1;

  f32x4 acc[4][4];
#pragma unroll
  for (int mt = 0; mt < 4; ++mt)
#pragma unroll
    for (int nt = 0; nt < 4; ++nt) acc[mt][nt] = (f32x4){0.f, 0.f, 0.f, 0.f};

  for (int wb = 0; wb < 8; ++wb) {
#pragma unroll
    for (int i = 0; i < 4; ++i) {
      const int id = t + (i << 8);
      const int row = id >> 3, q = id & 7;
      const uint4 pk = *(const uint4*)(v_pk + (size_t)bc * NHW + wb * 8192 +
                                       (size_t)(h0 + row) * 32 + q * 4);
      const ushort4 hi4 =
          make_ushort4((ushort_t)(pk.x & 0xffff), (ushort_t)(pk.y & 0xffff),
                       (ushort_t)(pk.z & 0xffff), (ushort_t)(pk.w & 0xffff));
      const ushort4 lo4 =
          make_ushort4((ushort_t)(pk.x >> 16), (ushort_t)(pk.y >> 16),
                       (ushort_t)(pk.z >> 16), (ushort_t)(pk.w >> 16));
      *(ushort4*)(vh + row * 40 + q * 4) = hi4;
      *(ushort4*)(vl + row * 40 + q * 4) = lo4;
    }
#pragma unroll
    for (int i = 0; i < 4; ++i) {
      const int id = t + (i << 8);
      const int arr = id >> 9, rem = id & 511;
      const int row = rem >> 2, q = rem & 3;
      const ushort_t* g = (arr ? pt_lo : pt_hi) + (size_t)bc * NHW +
                          wb * 8192 + (size_t)(v0 + row) * 32 + q * 8;
      ushort_t* d = (arr ? pl : ph) + row * 40 + q * 8;
      *(uint4*)d = *(const uint4*)g;
    }
    __syncthreads();
    bf16x8 aH[4], aL[4];
#pragma unroll
    for (int mt = 0; mt < 4; ++mt) {
      const int off = (wh * 64 + mt * 16 + (lane & 15)) * 40 + (lane >> 4) * 8;
      aH[mt] = *(const bf16x8*)(vh + off);
      aL[mt] = *(const bf16x8*)(vl + off);
    }
#pragma unroll
    for (int nt = 0; nt < 4; ++nt) {
      const int off = (wv * 64 + nt * 16 + (lane & 15)) * 40 + (lane >> 4) * 8;
      const bf16x8 bH = *(const bf16x8*)(ph + off);
      const bf16x8 bL = *(const bf16x8*)(pl + off);
#pragma unroll
      for (int mt = 0; mt < 4; ++mt) {
        acc[mt][nt] = __builtin_amdgcn_mfma_f32_16x16x32_bf16(aH[mt], bH, acc[mt][nt], 0, 0, 0);
        acc[mt][nt] = __builtin_amdgcn_mfma_f32_16x16x32_bf16(aH[mt], bL, acc[mt][nt], 0, 0, 0);
        acc[mt][nt] = __builtin_amdgcn_mfma_f32_16x16x32_bf16(aL[mt], bH, acc[mt][nt], 0, 0, 0);
      }
    }
    __syncthreads();
  }

  // LDS-staged epilogue: two 64-row chunks, contiguous float4 row writes
#pragma unroll 1
  for (int c = 0; c < 2; ++c) {
    if (c) __syncthreads();  // prior chunk's est reads done
    if (wh == c) {
#pragma unroll
      for (int mt = 0; mt < 4; ++mt) {
        const int row = mt * 16 + (lane >> 4) * 4;
#pragma unroll
        for (int nt = 0; nt < 4; ++nt) {
          const int col = wv * 64 + nt * 16 + (lane & 15);
#pragma unroll
          for (int r = 0; r < 4; ++r) est[(row + r) * 132 + col] = acc[mt][nt][r];
        }
      }
    }
    __syncthreads();
    float* ob = aout + (size_t)bc * NHW + (size_t)(h0 + c * 64) * NW + v0;
#pragma unroll
    for (int i = 0; i < 8; ++i) {
      const int idx = t + 256 * i;  // 2048 float4 = 64 rows x 32
      const int row = idx >> 5, c4 = (idx & 31) << 2;
      *(float4*)(ob + (size_t)row * NW + c4) = *(const float4*)&est[row * 132 + c4];
    }
  }
}

extern "C" void kernel_launch(void* const* d_in, const int* in_sizes, int n_in,
                              void* d_out, int out_size, void* d_ws,
                              size_t ws_size, hipStream_t stream) {
  const float* x = (const float*)d_in[0];
  const float* qkv_w = (const float*)d_in[1];
  const float* qkv_b = (const float*)d_in[2];
  const float* dw_w = (const float*)d_in[3];
  const float* dw_b = (const float*)d_in[4];
  const float* temp = (const float*)d_in[5];
  const float* proj_w = (const float*)d_in[6];
  const float* proj_b = (const float*)d_in[7];
  float* out = (float*)d_out;

  auto need = [](int nb) -> size_t {
    return (size_t)nb * 154140672ull + 147456ull;
  };
  int nb = 1;
  if (need(4) <= ws_size) nb = 4;
  else if (need(2) <= ws_size) nb = 2;

  char* base = (char*)d_ws;
  const size_t QKV_T = (size_t)nb * 75497472ull;  // region reserved; packed uses 1/2
  const size_t HALF = (size_t)nb * 12582912ull;
  const size_t NQB = (size_t)nb * 1572864ull;
  unsigned* qkv_tiled = (unsigned*)base;  // packed u32, nb*37748736 bytes
  ushort_t* pt_hi = (ushort_t*)base;      // alias (qkv dead after dw3)
  ushort_t* pt_lo = (ushort_t*)(base + HALF);
  float* aout = (float*)(base + 2 * HALF);
  char* p = base + QKV_T;
  ushort_t* qt_hi = (ushort_t*)p; p += HALF;
  ushort_t* qt_lo = (ushort_t*)p; p += HALF;
  ushort_t* kt_hi = (ushort_t*)p; p += HALF;
  ushort_t* kt_lo = (ushort_t*)p; p += HALF;
  unsigned* v_pk = (unsigned*)p; p += 2 * HALF;
  float* nq_p = (float*)p; p += NQB;
  float* nk_p = (float*)p; p += NQB;
  ushort_t* wq_hi = (ushort_t*)p; p += 55296;
  ushort_t* wq_lo = (ushort_t*)p; p += 55296;
  ushort_t* wp_hi = (ushort_t*)p; p += 18432;
  ushort_t* wp_lo = (ushort_t*)p;

  k_wprep<<<dim3(144), 256, 0, stream>>>(qkv_w, proj_w, wq_hi, wq_lo, wp_hi, wp_lo);

  const int BC = nb * NC;
  for (int b0 = 0; b0 < 4; b0 += nb) {
    const float* xb = x + (size_t)b0 * NC * NHW;
    float* outb = out + (size_t)b0 * NC * NHW;
    k_conv<NC3, true><<<dim3(1024, nb), 256, 0, stream>>>(
        xb, wq_hi, wq_lo, qkv_b, (float*)qkv_tiled);
    k_dw3<<<dim3(16, nb * NC3), 256, 0, stream>>>(
        qkv_tiled, dw_w, dw_b, qt_hi, qt_lo, kt_hi, kt_lo, v_pk, nq_p, nk_p);
    k_attn_mfma<<<dim3(BC * 4), 256, 0, stream>>>(
        qt_hi, qt_lo, kt_hi, kt_lo, nq_p, nk_p, temp, pt_hi, pt_lo);
    k_av_mfma<<<dim3(BC * 4), 256, 0, stream>>>(v_pk, pt_hi, pt_lo, aout);
    k_conv<NC, false><<<dim3(1024, nb), 256, 0, stream>>>(
        aout, wp_hi, wp_lo, proj_b, outb);
  }
}